// Round 1
// baseline (28.041 us; speedup 1.0000x reference)
//
#include <hip/hip_runtime.h>
#include <math.h>

// STP forward scan, restructured as an affine recurrence on r = imu/mu:
//   d[n] = a + (x[n-1]+x[n])/2
//   r[n] = exp(-d[n]) * (r[n-1] + x[n-1]/2) + x[n]/2
// td[n] = (r[n] > 0) ? 1 - r[n] : 1
// Chunk (500) boundaries: carry r is clamped (r>0 ? r : 1). Carry influence
// across one full chunk decays by exp(-500*a) <= ~1e-11, so each chunk's raw
// end value is computed carry-free in k1 via exact affine segment composition.

#define TDIM 50000
#define BDIM 8
#define UDIM 16
#define NCH 100    // chunks (T / 500)
#define SEGN 10    // segments per chunk
#define SLEN 50    // steps per segment
#define NSEQ 128   // B * U

struct alignas(16) AB { double A; double B; };

__device__ __forceinline__ float clean(float v) { return (v != v) ? 0.0f : v; }

__global__ __launch_bounds__(64) void stp_k1(
    const float* __restrict__ inp, const float* __restrict__ uu,
    const float* __restrict__ tauv, AB* __restrict__ ab)
{
    const int tid = blockIdx.x * 64 + threadIdx.x;
    const int sbu = tid & (NSEQ - 1);
    const int seg = tid >> 7;            // global segment 0..999
    const int u   = sbu & (UDIM - 1);
    const int b   = sbu >> 4;
    const int n0  = seg * SLEN;          // global start time of segment

    // Replicate reference f32 -> f64 promotion exactly:
    const float ui   = (fabsf(uu[u]) / 100.0f) * 100.0f;          // f32
    const float taui = fmaxf(fabsf(tauv[u]), 0.02001f) * 100.0f;  // f32
    const double a   = (double)(1.0f / taui);                     // f32 div, then f64

    const float* p = inp + ((size_t)b * TDIM + n0) * UDIM + u;
    double xp = 0.0;
    if (n0 != 0) xp = (double)(ui * clean(p[-UDIM]));

    // Exact affine composition over the segment: r_out = A*r_in + B
    double A = 1.0, Bc = 0.0;
#pragma unroll 5
    for (int t = 0; t < SLEN; ++t) {
        const double x = (double)(ui * clean(p[(size_t)t * UDIM]));  // f32 mul, then f64
        const double d = a + (xp + x) * 0.5;
        const double e = exp(-d);
        A *= e;
        Bc = e * (Bc + xp * 0.5) + x * 0.5;
        xp = x;
    }
    ab[tid].A = A;
    ab[tid].B = Bc;
}

__global__ __launch_bounds__(64) void stp_k2(
    const float* __restrict__ inp, const float* __restrict__ uu,
    const float* __restrict__ tauv, const AB* __restrict__ ab,
    float* __restrict__ out)
{
    const int tid = blockIdx.x * 64 + threadIdx.x;
    const int sbu = tid & (NSEQ - 1);
    const int seg = tid >> 7;
    const int c   = seg / SEGN;
    const int s   = seg - c * SEGN;
    const int u   = sbu & (UDIM - 1);
    const int b   = sbu >> 4;
    const int n0  = seg * SLEN;

    const float ui   = (fabsf(uu[u]) / 100.0f) * 100.0f;
    const float taui = fmaxf(fabsf(tauv[u]), 0.02001f) * 100.0f;
    const float af   = 1.0f / taui;

    // Chunk-entry carry (clamped) and raw value for the td shift, in f64.
    double r_in = 0.0;     // chunk 0 entry: imu0 = 0
    double td_prev = 1.0;  // out[0] uses the pad value 1.0
    if (c > 0) {
        const AB* q = ab + (size_t)(c - 1) * SEGN * NSEQ + sbu;
        double r = 0.0;    // carry-free: influence decayed below 1e-11
        #pragma unroll
        for (int j = 0; j < SEGN; ++j) {
            const AB e = q[(size_t)j * NSEQ];
            r = e.A * r + e.B;
        }
        r_in    = (r > 0.0) ? r : 1.0;         // clamped carry
        td_prev = (r > 0.0) ? 1.0 - r : 1.0;   // td from RAW end value
    }
    if (s > 0) {
        // compose intra-chunk prefix (raw, never clamped inside a chunk)
        const AB* q = ab + (size_t)c * SEGN * NSEQ + sbu;
        for (int j = 0; j < s; ++j) {
            const AB e = q[(size_t)j * NSEQ];
            r_in = e.A * r_in + e.B;
        }
        td_prev = (r_in > 0.0) ? 1.0 - r_in : 1.0;
    }

    const float* p = inp + ((size_t)b * TDIM + n0) * UDIM + u;
    float*       o = out + ((size_t)b * TDIM + n0) * UDIM + u;
    float xp = 0.0f;
    if (n0 != 0) xp = ui * clean(p[-UDIM]);

    float r   = (float)r_in;
    float tdp = (float)td_prev;
#pragma unroll 5
    for (int t = 0; t < SLEN; ++t) {
        const float ts = clean(p[(size_t)t * UDIM]);
        const float x  = ui * ts;
        const float d  = af + (xp + x) * 0.5f;
        const float e  = __expf(-d);
        r = e * (r + xp * 0.5f) + x * 0.5f;
        o[(size_t)t * UDIM] = ts * tdp;        // out[n] = tstim[n] * td[n-1]
        tdp = (r > 0.0f) ? 1.0f - r : 1.0f;
        xp = x;
    }
}

extern "C" void kernel_launch(void* const* d_in, const int* in_sizes, int n_in,
                              void* d_out, int out_size, void* d_ws, size_t ws_size,
                              hipStream_t stream) {
    const float* inp  = (const float*)d_in[0];
    const float* uu   = (const float*)d_in[1];
    const float* tauv = (const float*)d_in[2];
    float* out = (float*)d_out;
    AB* ab = (AB*)d_ws;  // needs 128000 * 16 B = 2,048,000 B of scratch

    const int total = NSEQ * NCH * SEGN;  // 128000 threads
    dim3 blk(64);
    dim3 grd(total / 64);                 // 2000 blocks (1 wave each)
    stp_k1<<<grd, blk, 0, stream>>>(inp, uu, tauv, ab);
    stp_k2<<<grd, blk, 0, stream>>>(inp, uu, tauv, ab, out);
}